// Round 11
// baseline (282.673 us; speedup 1.0000x reference)
//
#include <hip/hip_runtime.h>
#include <hip/hip_bf16.h>

#define EPS 1e-6f
#define H 512
#define W 512
#define NB 8
#define NC 8
#define NS 7
#define LOG2E 1.4426950408889634f

typedef float v2f __attribute__((ext_vector_type(2)));

__device__ __forceinline__ int refl(int t, int n) {
    if (t < 0) t = -t;
    if (t >= n) t = 2 * n - 2 - t;
    return t;
}

// ---------------- Kernel A: gaussian-smoothed max only ----------------------------
#define GW 256
#define GR 8
#define NBLK ((W / GW) * (H / GR))   // 128 slots per image

__global__ __launch_bounds__(256) void gauss_max_kernel(
    const float* __restrict__ est, const float* __restrict__ gauss,
    float* __restrict__ blockmax)
{
    const int tx = threadIdx.x, ty = threadIdx.y;
    const int x0 = blockIdx.x * GW;
    const int R  = blockIdx.y * GR + ty * 2;
    const int b  = blockIdx.z;
    const float* e = est + (size_t)b * H * W;
    const int c0 = x0 + tx * 4;

    const float g0 = sqrtf(gauss[0]);
    const float g1 = sqrtf(gauss[6]);
    const float g2 = sqrtf(gauss[12]);

    float4 h0, h1, h2, h3, h4;
    float m = 0.f;

#pragma unroll
    for (int k = 0; k < 6; k++) {
        const float* row = e + refl(R - 2 + k, H) * W;
        float4 v = *(const float4*)&row[c0];
        float em2 = __shfl_up(v.z, 1);
        float em1 = __shfl_up(v.w, 1);
        float ep1 = __shfl_down(v.x, 1);
        float ep2 = __shfl_down(v.y, 1);
        if (tx == 0) {
            if (x0 == 0) { em2 = v.z; em1 = v.y; }
            else         { em2 = row[c0 - 2]; em1 = row[c0 - 1]; }
        }
        if (tx == 63) {
            if (x0 + GW == W) { ep1 = v.z; ep2 = v.y; }
            else              { ep1 = row[c0 + 4]; ep2 = row[c0 + 5]; }
        }
        float4 hc;
        hc.x = g0 * (em2 + v.z) + g1 * (em1 + v.y) + g2 * v.x;
        hc.y = g0 * (em1 + v.w) + g1 * (v.x + v.z) + g2 * v.y;
        hc.z = g0 * (v.x + ep1) + g1 * (v.y + v.w) + g2 * v.z;
        hc.w = g0 * (v.y + ep2) + g1 * (v.z + ep1) + g2 * v.w;
        h0 = h1; h1 = h2; h2 = h3; h3 = h4; h4 = hc;
        if (k >= 4) {
            float ux = g0 * (h0.x + h4.x) + g1 * (h1.x + h3.x) + g2 * h2.x;
            float uy = g0 * (h0.y + h4.y) + g1 * (h1.y + h3.y) + g2 * h2.y;
            float uz = g0 * (h0.z + h4.z) + g1 * (h1.z + h3.z) + g2 * h2.z;
            float uw = g0 * (h0.w + h4.w) + g1 * (h1.w + h3.w) + g2 * h2.w;
            m = fmaxf(m, fmaxf(fmaxf(ux, uy), fmaxf(uz, uw)));
        }
    }

#pragma unroll
    for (int off = 32; off > 0; off >>= 1)
        m = fmaxf(m, __shfl_xor(m, off, 64));
    __shared__ float wm[4];
    if (tx == 0) wm[ty] = m;
    __syncthreads();
    if (tx == 0 && ty == 0) {
        float mm = fmaxf(fmaxf(wm[0], wm[1]), fmaxf(wm[2], wm[3]));
        blockmax[b * NBLK + blockIdx.y * gridDim.x + blockIdx.x] = mm;
    }
}

// ---------------- Kernel B: register-streaming stage, paired rows -----------------
// 1 wave = 64-col band (outputs lanes 3..60 = 58 cols), SLAB=16 rows per wave,
// TWO z-rows per iteration (shared windows, halved bookkeeping, 2x ILP). No LDS.
#define SLAB 16
#define BANDW 58
#define NBANDS 9

__global__ __launch_bounds__(64) void stage_kernel(
    const float* __restrict__ est, const float* __restrict__ noisy,
    const float* __restrict__ blockmax,
    const float* __restrict__ filt,
    const float* __restrict__ wv, const float* __restrict__ bv,
    const float* __restrict__ lamp, const float* __restrict__ gatep,
    const float* __restrict__ gauss,
    float* __restrict__ out)
{
    const int l = threadIdx.x;
    const int band = blockIdx.x;
    const int R = blockIdx.y * SLAB;
    const int b = blockIdx.z;

    const float* e  = est   + (size_t)b * H * W;
    const float* nz = noisy + (size_t)b * H * W;
    float*       op = out   + (size_t)b * H * W;

    const int c = band * BANDW - 3 + l;
    const int ci0 = refl(c - 2, W), ci1 = refl(c - 1, W), ci2 = refl(c, W),
              ci3 = refl(c + 1, W), ci4 = refl(c + 2, W);
    const int cc = c < 0 ? 0 : (c > W - 1 ? W - 1 : c);
    const bool c_in = (c >= 0) && (c < W);
    const bool c_st = (l >= 3) && (l <= 60) && (c < W);

    // packed filters fp[k][j] = {f[2j][k], f[2j+1][k]}  (uniform)
    v2f fp[9][4], w2p[4], b2p[4];
#pragma unroll
    for (int j = 0; j < 4; j++) {
#pragma unroll
        for (int k = 0; k < 9; k++)
            fp[k][j] = (v2f){filt[(2 * j) * 9 + k], filt[(2 * j + 1) * 9 + k]};
        w2p[j] = (v2f){wv[2 * j] * (2.f * LOG2E), wv[2 * j + 1] * (2.f * LOG2E)};
        b2p[j] = (v2f){bv[2 * j] * (2.f * LOG2E), bv[2 * j + 1] * (2.f * LOG2E)};
    }

    const float g0 = sqrtf(gauss[0]);
    const float g1 = sqrtf(gauss[6]);
    const float g2 = sqrtf(gauss[12]);
    const float lam = lamp[0];
    const float g = __builtin_amdgcn_rcpf(1.f + __builtin_amdgcn_exp2f(-gatep[0] * LOG2E));

    float m = fmaxf(blockmax[b * NBLK + l], blockmax[b * NBLK + 64 + l]);
#pragma unroll
    for (int off = 32; off > 0; off >>= 1)
        m = fmaxf(m, __shfl_xor(m, off, 64));
    const float dinv = __builtin_amdgcn_rcpf(fmaxf(m, EPS));

    auto ld5 = [&](int r, float& m2, float& m1, float& v, float& p1, float& p2) {
        const float* rb = e + (size_t)refl(r, H) * W;
        m2 = rb[ci0]; m1 = rb[ci1]; v = rb[ci2]; p1 = rb[ci3]; p2 = rb[ci4];
    };
    auto hof = [&](float m2, float m1, float v, float p1, float p2) -> float {
        return g0 * (m2 + p2) + g1 * (m1 + p1) + g2 * v;
    };
    auto ldn = [&](int r) -> float {
        int rr = r < 0 ? 0 : (r > H - 1 ? H - 1 : r);
        return nz[(size_t)rr * W + cc];
    };

    // ---- prologue ----
    // h window: rows R-3..R ; est window slots 0..2 = rows R-2, R-1, R (m1,v,p1)
    float hA, hB, hC, hD;
    float wm1_0, wv0_0, wp1_0, wm1_1, wv0_1, wp1_1, wm1_2, wv0_2, wp1_2;
    {
        float m2, m1, v, p1, p2;
        ld5(R - 3, m2, m1, v, p1, p2); hA = hof(m2, m1, v, p1, p2);
        ld5(R - 2, m2, m1, v, p1, p2); hB = hof(m2, m1, v, p1, p2);
        wm1_0 = m1; wv0_0 = v; wp1_0 = p1;
        ld5(R - 1, m2, m1, v, p1, p2); hC = hof(m2, m1, v, p1, p2);
        wm1_1 = m1; wv0_1 = v; wp1_1 = p1;
        ld5(R - 0, m2, m1, v, p1, p2); hD = hof(m2, m1, v, p1, p2);
        wm1_2 = m1; wv0_2 = v; wp1_2 = p1;
    }
    // est queue: rows R+1..R+4 (popped two per iter)
    float q0m2, q0m1, q0v, q0p1, q0p2;
    float q1m2, q1m1, q1v, q1p1, q1p2;
    float q2m2, q2m1, q2v, q2p1, q2p2;
    float q3m2, q3m1, q3v, q3p1, q3p2;
    ld5(R + 1, q0m2, q0m1, q0v, q0p1, q0p2);
    ld5(R + 2, q1m2, q1m1, q1v, q1p1, q1p2);
    ld5(R + 3, q2m2, q2m1, q2v, q2p1, q2p2);
    ld5(R + 4, q3m2, q3m1, q3v, q3p1, q3p2);
    // noisy queue: rows R-2..R+1
    float nq0 = ldn(R - 2), nq1 = ldn(R - 1), nq2 = ldn(R), nq3 = ldn(R + 1);

    float aU0 = 0.f, aV0 = 0.f, aW0 = 0.f;
    float aU1 = 0.f, aV1 = 0.f, aW1 = 0.f;
    float iwp = 0.f;   // iw(t-1) entering each iteration

#pragma unroll 1
    for (int i = 0; i < SLAB / 2 + 1; ++i) {
        const int t = R - 1 + 2 * i;   // z-rows t, t+1 ; outputs rows t-1, t (i>=1)

        // pop est rows t+2, t+3 ; shift ; refill rows t+6, t+7
        float e2m2 = q0m2, e2m1 = q0m1, e2v = q0v, e2p1 = q0p1, e2p2 = q0p2;
        float e3m2 = q1m2, e3m1 = q1m1, e3v = q1v, e3p1 = q1p1, e3p2 = q1p2;
        q0m2 = q2m2; q0m1 = q2m1; q0v = q2v; q0p1 = q2p1; q0p2 = q2p2;
        q1m2 = q3m2; q1m1 = q3m1; q1v = q3v; q1p1 = q3p1; q1p2 = q3p2;
        ld5(t + 6, q2m2, q2m1, q2v, q2p1, q2p2);
        ld5(t + 7, q3m2, q3m1, q3v, q3p1, q3p2);
        // pop noisy rows t-1, t ; refill rows t+3, t+4
        float n0 = nq0, n1 = nq1;
        nq0 = nq2; nq1 = nq3; nq2 = ldn(t + 3); nq3 = ldn(t + 4);

        // h rows t+2, t+3 ; iw for z-rows t, t+1
        float h4 = hof(e2m2, e2m1, e2v, e2p1, e2p2);
        float h5 = hof(e3m2, e3m1, e3v, e3p1, e3p2);
        float iw_t  = fmaxf((g0 * (hA + h4) + g1 * (hB + hD) + g2 * hC) * dinv, EPS);
        float iw_t1 = fmaxf((g0 * (hB + h5) + g1 * (hC + h4) + g2 * hD) * dinv, EPS);
        if (!(c_in && t >= 0 && t < H))         iw_t  = 0.f;   // zero-pad transpose conv
        if (!(c_in && t + 1 >= 0 && t + 1 < H)) iw_t1 = 0.f;
        hA = hC; hB = hD; hC = h4; hD = h5;

        // analysis: row t taps = slots 0..2 ; row t+1 taps = slots 1,2 + e2
        const float taA[9] = {wm1_0, wv0_0, wp1_0, wm1_1, wv0_1, wp1_1, wm1_2, wv0_2, wp1_2};
        const float taB[9] = {wm1_1, wv0_1, wp1_1, wm1_2, wv0_2, wp1_2, e2m1, e2v, e2p1};
        v2f ra[4] = {{0,0},{0,0},{0,0},{0,0}};
        v2f rb[4] = {{0,0},{0,0},{0,0},{0,0}};
#pragma unroll
        for (int k = 0; k < 9; k++) {
            v2f ea = (v2f){taA[k], taA[k]};
            v2f eb = (v2f){taB[k], taB[k]};
#pragma unroll
            for (int j = 0; j < 4; j++) {
                ra[j] += fp[k][j] * ea;
                rb[j] += fp[k][j] * eb;
            }
        }
        // activation: z = iw * tanh(w*r+b)  (exp2 domain)
        v2f zpa[4], zpb[4];
        const v2f iwa2 = (v2f){iw_t, iw_t}, iwb2 = (v2f){iw_t1, iw_t1};
#pragma unroll
        for (int j = 0; j < 4; j++) {
            v2f wra = w2p[j] * ra[j] + b2p[j];
            v2f wrb = w2p[j] * rb[j] + b2p[j];
            v2f tha = (v2f){1.f - 2.f * __builtin_amdgcn_rcpf(__builtin_amdgcn_exp2f(wra.x) + 1.f),
                            1.f - 2.f * __builtin_amdgcn_rcpf(__builtin_amdgcn_exp2f(wra.y) + 1.f)};
            v2f thb = (v2f){1.f - 2.f * __builtin_amdgcn_rcpf(__builtin_amdgcn_exp2f(wrb.x) + 1.f),
                            1.f - 2.f * __builtin_amdgcn_rcpf(__builtin_amdgcn_exp2f(wrb.y) + 1.f)};
            zpa[j] = iwa2 * tha;
            zpb[j] = iwb2 * thb;
        }
        // synthesis partials per z-row: qa[k] = sum_ch f[ch][k] z[ch]
        float qa[9], qb[9];
#pragma unroll
        for (int k = 0; k < 9; k++) {
            v2f sA = fp[k][0] * zpa[0] + fp[k][1] * zpa[1]
                   + fp[k][2] * zpa[2] + fp[k][3] * zpa[3];
            v2f sB = fp[k][0] * zpb[0] + fp[k][1] * zpb[1]
                   + fp[k][2] * zpb[2] + fp[k][3] * zpb[3];
            qa[k] = sA.x + sA.y;
            qb[k] = sB.x + sB.y;
        }
        // paired accumulator rotation:
        // diff(t-1) = acc0 + q2(t) ; diff(t) = acc1 + q1(t) + q2(t+1)
        // acc0' = q0(t) + q1(t+1) ; acc1' = q0(t+1)
        float dAU = aU0 + qa[6], dAV = aV0 + qa[7], dAW = aW0 + qa[8];
        float dBU = aU1 + qa[3] + qb[6], dBV = aV1 + qa[4] + qb[7], dBW = aW1 + qa[5] + qb[8];
        aU0 = qa[0] + qb[3]; aV0 = qa[1] + qb[4]; aW0 = qa[2] + qb[5];
        aU1 = qb[0];         aV1 = qb[1];         aW1 = qb[2];
        float diffA = __shfl_up(dAU, 1) + dAV + __shfl_down(dAW, 1);
        float diffB = __shfl_up(dBU, 1) + dBV + __shfl_down(dBW, 1);

        if (i >= 1 && c_st) {
            // output row t-1: est center = wv0_0 (slot0), iwc = iwp, noisy n0
            float eoa = wv0_0;
            float fga = (eoa - n0) * __builtin_amdgcn_rcpf(eoa * eoa + EPS);
            float e2a = eoa - diffA - lam * iwp * fga;
            float ena = e2a + g * (n0 - e2a);
            ena = fminf(fmaxf(ena, EPS), 1.f);
            op[(size_t)(t - 1) * W + c] = ena;
            // output row t: est center = wv0_1 (slot1), iwc = iw_t, noisy n1
            float eob = wv0_1;
            float fgb = (eob - n1) * __builtin_amdgcn_rcpf(eob * eob + EPS);
            float e2b = eob - diffB - lam * iw_t * fgb;
            float enb = e2b + g * (n1 - e2b);
            enb = fminf(fmaxf(enb, EPS), 1.f);
            op[(size_t)t * W + c] = enb;
        }
        iwp = iw_t1;

        // shift est window by 2: slots <- (row t+1, t+2, t+3)
        wm1_0 = wm1_2; wv0_0 = wv0_2; wp1_0 = wp1_2;
        wm1_1 = e2m1;  wv0_1 = e2v;   wp1_1 = e2p1;
        wm1_2 = e3m1;  wv0_2 = e3v;   wp1_2 = e3p1;
    }
}

extern "C" void kernel_launch(void* const* d_in, const int* in_sizes, int n_in,
                              void* d_out, int out_size, void* d_ws, size_t ws_size,
                              hipStream_t stream)
{
    const float* noisy   = (const float*)d_in[0];
    const float* filters = (const float*)d_in[1];  // [7][8][1][3][3]
    const float* wv      = (const float*)d_in[2];  // [7][8]
    const float* bv      = (const float*)d_in[3];  // [7][8]
    const float* lam     = (const float*)d_in[4];  // [7]
    const float* gate    = (const float*)d_in[5];  // [7]
    const float* gauss   = (const float*)d_in[6];  // [25]
    float* out = (float*)d_out;

    char* ws = (char*)d_ws;
    float* ws0      = (float*)ws;                    // 8 MB ping buffer
    float* blockmax = (float*)(ws + (8u << 20));     // 128*8 floats, rewritten each stage

    const float* cur = noisy;
    for (int s = 0; s < NS; s++) {
        float* nxt = (s % 2 == 0) ? out : ws0;  // odd stage count -> final lands in out
        gauss_max_kernel<<<dim3(W / GW, H / GR, NB), dim3(64, 4), 0, stream>>>(
            cur, gauss, blockmax);
        stage_kernel<<<dim3(NBANDS, H / SLAB, NB), dim3(64), 0, stream>>>(
            cur, noisy, blockmax,
            filters + s * NC * 9, wv + s * NC, bv + s * NC, lam + s, gate + s, gauss, nxt);
        cur = nxt;
    }
}

// Round 12
// 263.725 us; speedup vs baseline: 1.0718x; 1.0718x over previous
//
#include <hip/hip_runtime.h>
#include <hip/hip_bf16.h>

#define EPS 1e-6f
#define H 512
#define W 512
#define NB 8
#define NC 8
#define NS 7
#define LOG2E 1.4426950408889634f

typedef float v2f __attribute__((ext_vector_type(2)));

__device__ __forceinline__ int refl(int t, int n) {
    if (t < 0) t = -t;
    if (t >= n) t = 2 * n - 2 - t;
    return t;
}

// ---------------- Kernel A: gaussian-smoothed max only ----------------------------
#define GW 256
#define GR 8
#define NBLK ((W / GW) * (H / GR))   // 128 slots per image

__global__ __launch_bounds__(256) void gauss_max_kernel(
    const float* __restrict__ est, const float* __restrict__ gauss,
    float* __restrict__ blockmax)
{
    const int tx = threadIdx.x, ty = threadIdx.y;
    const int x0 = blockIdx.x * GW;
    const int R  = blockIdx.y * GR + ty * 2;
    const int b  = blockIdx.z;
    const float* e = est + (size_t)b * H * W;
    const int c0 = x0 + tx * 4;

    const float g0 = sqrtf(gauss[0]);
    const float g1 = sqrtf(gauss[6]);
    const float g2 = sqrtf(gauss[12]);

    float4 h0, h1, h2, h3, h4;
    float m = 0.f;

#pragma unroll
    for (int k = 0; k < 6; k++) {
        const float* row = e + refl(R - 2 + k, H) * W;
        float4 v = *(const float4*)&row[c0];
        float em2 = __shfl_up(v.z, 1);
        float em1 = __shfl_up(v.w, 1);
        float ep1 = __shfl_down(v.x, 1);
        float ep2 = __shfl_down(v.y, 1);
        if (tx == 0) {
            if (x0 == 0) { em2 = v.z; em1 = v.y; }
            else         { em2 = row[c0 - 2]; em1 = row[c0 - 1]; }
        }
        if (tx == 63) {
            if (x0 + GW == W) { ep1 = v.z; ep2 = v.y; }
            else              { ep1 = row[c0 + 4]; ep2 = row[c0 + 5]; }
        }
        float4 hc;
        hc.x = g0 * (em2 + v.z) + g1 * (em1 + v.y) + g2 * v.x;
        hc.y = g0 * (em1 + v.w) + g1 * (v.x + v.z) + g2 * v.y;
        hc.z = g0 * (v.x + ep1) + g1 * (v.y + v.w) + g2 * v.z;
        hc.w = g0 * (v.y + ep2) + g1 * (v.z + ep1) + g2 * v.w;
        h0 = h1; h1 = h2; h2 = h3; h3 = h4; h4 = hc;
        if (k >= 4) {
            float ux = g0 * (h0.x + h4.x) + g1 * (h1.x + h3.x) + g2 * h2.x;
            float uy = g0 * (h0.y + h4.y) + g1 * (h1.y + h3.y) + g2 * h2.y;
            float uz = g0 * (h0.z + h4.z) + g1 * (h1.z + h3.z) + g2 * h2.z;
            float uw = g0 * (h0.w + h4.w) + g1 * (h1.w + h3.w) + g2 * h2.w;
            m = fmaxf(m, fmaxf(fmaxf(ux, uy), fmaxf(uz, uw)));
        }
    }

#pragma unroll
    for (int off = 32; off > 0; off >>= 1)
        m = fmaxf(m, __shfl_xor(m, off, 64));
    __shared__ float wm[4];
    if (tx == 0) wm[ty] = m;
    __syncthreads();
    if (tx == 0 && ty == 0) {
        float mm = fmaxf(fmaxf(wm[0], wm[1]), fmaxf(wm[2], wm[3]));
        blockmax[b * NBLK + blockIdx.y * gridDim.x + blockIdx.x] = mm;
    }
}

// ---------------- Kernel B: register-streaming stage (R8 base) --------------------
// 1 wave = 64-col band (outputs lanes 3..60). No LDS. 5-tap direct loads,
// depth-4 prefetch queues, paired-rcp tanh (12 trans ops/px instead of 16).
#define SLAB 8
#define BANDW 58
#define NBANDS 9

__global__ __launch_bounds__(64) void stage_kernel(
    const float* __restrict__ est, const float* __restrict__ noisy,
    const float* __restrict__ blockmax,
    const float* __restrict__ filt,
    const float* __restrict__ wv, const float* __restrict__ bv,
    const float* __restrict__ lamp, const float* __restrict__ gatep,
    const float* __restrict__ gauss,
    float* __restrict__ out)
{
    const int l = threadIdx.x;
    const int band = blockIdx.x;
    const int R = blockIdx.y * SLAB;
    const int b = blockIdx.z;

    const float* e  = est   + (size_t)b * H * W;
    const float* nz = noisy + (size_t)b * H * W;
    float*       op = out   + (size_t)b * H * W;

    const int c = band * BANDW - 3 + l;
    const int ci0 = refl(c - 2, W), ci1 = refl(c - 1, W), ci2 = refl(c, W),
              ci3 = refl(c + 1, W), ci4 = refl(c + 2, W);
    const int cc = c < 0 ? 0 : (c > W - 1 ? W - 1 : c);
    const bool c_in = (c >= 0) && (c < W);
    const bool c_st = (l >= 3) && (l <= 60) && (c < W);

    // packed filters: fp[k][j] = {f[2j][k], f[2j+1][k]} (uniform -> SGPRs)
    v2f fp[9][4], w2p[4], b2p[4];
#pragma unroll
    for (int j = 0; j < 4; j++) {
#pragma unroll
        for (int k = 0; k < 9; k++)
            fp[k][j] = (v2f){filt[(2 * j) * 9 + k], filt[(2 * j + 1) * 9 + k]};
        w2p[j] = (v2f){wv[2 * j] * (2.f * LOG2E), wv[2 * j + 1] * (2.f * LOG2E)};
        b2p[j] = (v2f){bv[2 * j] * (2.f * LOG2E), bv[2 * j + 1] * (2.f * LOG2E)};
    }

    const float g0 = sqrtf(gauss[0]);
    const float g1 = sqrtf(gauss[6]);
    const float g2 = sqrtf(gauss[12]);
    const float lam = lamp[0];
    const float g = __builtin_amdgcn_rcpf(1.f + __builtin_amdgcn_exp2f(-gatep[0] * LOG2E));

    float m = fmaxf(blockmax[b * NBLK + l], blockmax[b * NBLK + 64 + l]);
#pragma unroll
    for (int off = 32; off > 0; off >>= 1)
        m = fmaxf(m, __shfl_xor(m, off, 64));
    const float dinv = __builtin_amdgcn_rcpf(fmaxf(m, EPS));

    auto ld5 = [&](int r, float& m2, float& m1, float& v, float& p1, float& p2) {
        const float* rb = e + (size_t)refl(r, H) * W;
        m2 = rb[ci0]; m1 = rb[ci1]; v = rb[ci2]; p1 = rb[ci3]; p2 = rb[ci4];
    };
    auto hof = [&](float m2, float m1, float v, float p1, float p2) -> float {
        return g0 * (m2 + p2) + g1 * (m1 + p1) + g2 * v;
    };
    auto ldn = [&](int r) -> float {
        int rr = r < 0 ? 0 : (r > H - 1 ? H - 1 : r);
        return nz[(size_t)rr * W + cc];
    };

    // prologue: h for rows R-3..R; est windows (m1,v,p1) rows R-2..R in slots 1..3
    float h[5];
    float wm1[4], wvv[4], wp1[4];
    {
        float m2, m1, v, p1, p2;
        ld5(R - 3, m2, m1, v, p1, p2); h[1] = hof(m2, m1, v, p1, p2);
        ld5(R - 2, m2, m1, v, p1, p2); h[2] = hof(m2, m1, v, p1, p2);
        wm1[1] = m1; wvv[1] = v; wp1[1] = p1;
        ld5(R - 1, m2, m1, v, p1, p2); h[3] = hof(m2, m1, v, p1, p2);
        wm1[2] = m1; wvv[2] = v; wp1[2] = p1;
        ld5(R - 0, m2, m1, v, p1, p2); h[4] = hof(m2, m1, v, p1, p2);
        wm1[3] = m1; wvv[3] = v; wp1[3] = p1;
    }
    // depth-4 prefetch queues: est rows R+1..R+4, noisy rows R-2..R+1
    float qm2[4], qm1[4], qv[4], qp1[4], qp2[4];
    ld5(R + 1, qm2[0], qm1[0], qv[0], qp1[0], qp2[0]);
    ld5(R + 2, qm2[1], qm1[1], qv[1], qp1[1], qp2[1]);
    ld5(R + 3, qm2[2], qm1[2], qv[2], qp1[2], qp2[2]);
    ld5(R + 4, qm2[3], qm1[3], qv[3], qp1[3], qp2[3]);
    float nq0 = ldn(R - 2), nq1 = ldn(R - 1), nq2 = ldn(R), nq3 = ldn(R + 1);
    wm1[0] = 0.f; wvv[0] = 0.f; wp1[0] = 0.f; h[0] = 0.f;

    v2f aU0 = {0,0}, aV0 = {0,0}, aW0 = {0,0};
    v2f aU1 = {0,0}, aV1 = {0,0}, aW1 = {0,0};
    float iw_prev = 0.f;

#pragma unroll 2
    for (int i = 0; i < SLAB + 2; ++i) {
        const int t = R - 1 + i;

        // pop 5-tap tuple (row t+2); refill with row t+6 (4 iterations ahead)
        float m2 = qm2[0], m1 = qm1[0], v = qv[0], p1 = qp1[0], p2 = qp2[0];
        qm2[0] = qm2[1]; qm1[0] = qm1[1]; qv[0] = qv[1]; qp1[0] = qp1[1]; qp2[0] = qp2[1];
        qm2[1] = qm2[2]; qm1[1] = qm1[2]; qv[1] = qv[2]; qp1[1] = qp1[2]; qp2[1] = qp2[2];
        qm2[2] = qm2[3]; qm1[2] = qm1[3]; qv[2] = qv[3]; qp1[2] = qp1[3]; qp2[2] = qp2[3];
        ld5(t + 6, qm2[3], qm1[3], qv[3], qp1[3], qp2[3]);
        float n0 = nq0; nq0 = nq1; nq1 = nq2; nq2 = nq3; nq3 = ldn(t + 3);

        float hnew = hof(m2, m1, v, p1, p2);
        h[0] = h[1]; h[1] = h[2]; h[2] = h[3]; h[3] = h[4]; h[4] = hnew;
        float iw = fmaxf((g0 * (h[0] + h[4]) + g1 * (h[1] + h[3]) + g2 * h[2]) * dinv, EPS);
        const bool rin = (t >= 0) && (t < H);
        if (!(c_in && rin)) iw = 0.f;    // zero-pad of transpose conv

        wm1[0] = wm1[1]; wvv[0] = wvv[1]; wp1[0] = wp1[1];
        wm1[1] = wm1[2]; wvv[1] = wvv[2]; wp1[1] = wp1[2];
        wm1[2] = wm1[3]; wvv[2] = wvv[3]; wp1[2] = wp1[3];
        wm1[3] = m1;     wvv[3] = v;      wp1[3] = p1;

        // analysis conv on rows t-1..t+1 (slots 0..2), channel pairs in v2f
        float ew[9] = {wm1[0], wvv[0], wp1[0],
                       wm1[1], wvv[1], wp1[1],
                       wm1[2], wvv[2], wp1[2]};
        v2f r4[4] = {{0,0},{0,0},{0,0},{0,0}};
#pragma unroll
        for (int k = 0; k < 9; k++) {
            v2f es = (v2f){ew[k], ew[k]};
            r4[0] += fp[k][0] * es;
            r4[1] += fp[k][1] * es;
            r4[2] += fp[k][2] * es;
            r4[3] += fp[k][3] * es;
        }
        // tanh(w*r+b) in exp2 domain with PAIRED rcp:
        // 1/(a0+1), 1/(a1+1) from one rcp((a0+1)(a1+1))
        v2f zp[4];
        v2f iwv = (v2f){iw, iw};
#pragma unroll
        for (int j = 0; j < 4; j++) {
            v2f wr = w2p[j] * r4[j] + b2p[j];
            float s0 = __builtin_amdgcn_exp2f(wr.x) + 1.f;
            float s1 = __builtin_amdgcn_exp2f(wr.y) + 1.f;
            float rp = __builtin_amdgcn_rcpf(s0 * s1);
            v2f th = (v2f){1.f - 2.f * (rp * s1), 1.f - 2.f * (rp * s0)};
            zp[j] = iwv * th;
        }
        // synthesis partials (channel pairs)
        v2f U0 = {0,0}, V0 = {0,0}, W0 = {0,0};
        v2f U1 = {0,0}, V1 = {0,0}, W1 = {0,0};
        v2f U2 = {0,0}, V2 = {0,0}, W2 = {0,0};
#pragma unroll
        for (int j = 0; j < 4; j++) {
            U0 += fp[0][j] * zp[j]; V0 += fp[1][j] * zp[j]; W0 += fp[2][j] * zp[j];
            U1 += fp[3][j] * zp[j]; V1 += fp[4][j] * zp[j]; W1 += fp[5][j] * zp[j];
            U2 += fp[6][j] * zp[j]; V2 += fp[7][j] * zp[j]; W2 += fp[8][j] * zp[j];
        }
        v2f dU = aU0 + U2, dV = aV0 + V2, dW = aW0 + W2;
        aU0 = aU1 + U1; aV0 = aV1 + V1; aW0 = aW1 + W1;
        aU1 = U0;       aV1 = V0;       aW1 = W0;
        float dUs = dU.x + dU.y, dVs = dV.x + dV.y, dWs = dW.x + dW.y;
        float diff = __shfl_up(dUs, 1) + dVs + __shfl_down(dWs, 1);

        if (i >= 2 && c_st) {
            float eo = wvv[0];     // est row t-1, center tap
            float fg = (eo - n0) * __builtin_amdgcn_rcpf(eo * eo + EPS);
            float est2 = eo - diff - lam * iw_prev * fg;
            float en = est2 + g * (n0 - est2);
            en = fminf(fmaxf(en, EPS), 1.f);
            op[(size_t)(t - 1) * W + c] = en;
        }
        iw_prev = iw;
    }
}

extern "C" void kernel_launch(void* const* d_in, const int* in_sizes, int n_in,
                              void* d_out, int out_size, void* d_ws, size_t ws_size,
                              hipStream_t stream)
{
    const float* noisy   = (const float*)d_in[0];
    const float* filters = (const float*)d_in[1];  // [7][8][1][3][3]
    const float* wv      = (const float*)d_in[2];  // [7][8]
    const float* bv      = (const float*)d_in[3];  // [7][8]
    const float* lam     = (const float*)d_in[4];  // [7]
    const float* gate    = (const float*)d_in[5];  // [7]
    const float* gauss   = (const float*)d_in[6];  // [25]
    float* out = (float*)d_out;

    char* ws = (char*)d_ws;
    float* ws0      = (float*)ws;                    // 8 MB ping buffer
    float* blockmax = (float*)(ws + (8u << 20));     // 128*8 floats, rewritten each stage

    const float* cur = noisy;
    for (int s = 0; s < NS; s++) {
        float* nxt = (s % 2 == 0) ? out : ws0;  // odd stage count -> final lands in out
        gauss_max_kernel<<<dim3(W / GW, H / GR, NB), dim3(64, 4), 0, stream>>>(
            cur, gauss, blockmax);
        stage_kernel<<<dim3(NBANDS, H / SLAB, NB), dim3(64), 0, stream>>>(
            cur, noisy, blockmax,
            filters + s * NC * 9, wv + s * NC, bv + s * NC, lam + s, gate + s, gauss, nxt);
        cur = nxt;
    }
}